// Round 9
// baseline (514.318 us; speedup 1.0000x reference)
//
#include <hip/hip_runtime.h>

// KPConv simple block: grid window + dense-MFMA KPConv + BN + LeakyReLU
// B=8, N=4096 -> M=32768; C_IN=64, C_OUT=128, K=15 kernel pts.
//
// Exact simplification: influence w = max(1 - d/0.04, 0) with ||kp||<=0.042
// => any candidate with ||rel|| >= 0.082 contributes w=0 for all 15 kernel
// points.  So NO neighbor lists are needed: per block (16 sorted queries)
// we run a DENSE matmul over the candidate window (cell bbox +1), where the
// influence matrix S is zero for non-neighbors by construction.
//
// R9: stage-1 as MFMA.  S[q*16+k][n] (bf16, k=15 row = 0) x F^T[c][n]
// (bf16, staged coalesced from feats) -> wf[q][c*16+k], chunks of 32 n.
// Kills R3-R8's LDS-broadcast bottleneck (~136 b128/query-wave -> ~18).
// k1_grid + fsorted/kf deleted.  p3 GEMM: kc' = c*16+k, K=1024 (k=15
// slots zero in both wf and Wt).

#define NB     8
#define NPTS   4096
#define M_TOT  32768
#define CIN    64
#define COUT   128
#define NKP    15
#define NCELL  1728            // 12^3
#define MAXROWS 64             // 16 sorted queries: yspan<=12 x zspan<=4
#define R2EFF  (0.082f * 0.082f)
#define KP_INV 25.0f           // 1 / KP_EXTENT(0.04)
#define NEG_SLOPE 0.2f
#define KCP    1024            // kc' dimension: c*16+k (k=15 slots zero)
#define WFPAD  1032            // wf row stride (shorts), 16B-aligned
#define SPAD   40              // S row stride (shorts), 80B, 16B-aligned
#define FTPAD  36              // FT row stride (shorts), 72B, 8B-aligned

typedef float f32x4_t __attribute__((ext_vector_type(4)));
typedef short bf16x8_t __attribute__((ext_vector_type(8)));
typedef short short4_t __attribute__((ext_vector_type(4)));

__device__ __forceinline__ unsigned short f2bf(float f) {
  union { float f; unsigned u; } v; v.f = f;
  unsigned r = v.u + 0x7FFF + ((v.u >> 16) & 1);   // RNE
  return (unsigned short)(r >> 16);
}
__device__ __forceinline__ int cell_of(float x, float y, float z) {
  int cx = (int)(x * 12.f); cx = cx > 11 ? 11 : cx;
  int cy = (int)(y * 12.f); cy = cy > 11 ? 11 : cy;
  int cz = (int)(z * 12.f); cz = cz > 11 ? 11 : cz;
  return (cz * 12 + cy) * 12 + cx;
}

// ---------------------------------------------------------------------------
// K0a: per-cell histogram
// ---------------------------------------------------------------------------
__global__ __launch_bounds__(256) void k0a_hist(
    const float* __restrict__ xyz, int* __restrict__ cellcnt)
{
  const int pt = blockIdx.x * 256 + threadIdx.x;
  const float x = xyz[pt * 3], y = xyz[pt * 3 + 1], z = xyz[pt * 3 + 2];
  const int b = pt >> 12;
  atomicAdd(&cellcnt[b * NCELL + cell_of(x, y, z)], 1);
}

// ---------------------------------------------------------------------------
// K0b: blocks 0..7 = per-batch exclusive scan; blocks 8..39 = W -> Wt
// Wt[d][c*16+k] bf16, k=15 slot zero (kc' ordering; K-dim = 1024).
// ---------------------------------------------------------------------------
__global__ __launch_bounds__(256) void k0b_scan_kW(
    const int* __restrict__ cellcnt, int* __restrict__ cellstart,
    const float* __restrict__ W, unsigned short* __restrict__ Wt)
{
  if (blockIdx.x >= 8) {
    const int idx = (blockIdx.x - 8) * 256 + threadIdx.x;  // 8192
    const int d = idx & 127, c = idx >> 7;                 // c 0..63
    union { unsigned short s[16]; uint4 v[2]; } u;
    #pragma unroll
    for (int k = 0; k < NKP; k++)
      u.s[k] = f2bf(W[(size_t)k * (CIN * COUT) + c * COUT + d]);
    u.s[15] = 0;
    uint4* dst = (uint4*)&Wt[(size_t)d * KCP + c * 16];
    dst[0] = u.v[0]; dst[1] = u.v[1];
    return;
  }
  __shared__ int ps[256];
  const int b = blockIdx.x, t = threadIdx.x;
  int local[7], s = 0;
  #pragma unroll
  for (int i = 0; i < 7; i++) {
    const int cid = t * 7 + i;
    const int c = (cid < NCELL) ? cellcnt[b * NCELL + cid] : 0;
    local[i] = c; s += c;
  }
  ps[t] = s; __syncthreads();
  for (int off = 1; off < 256; off <<= 1) {
    int v = (t >= off) ? ps[t - off] : 0;
    __syncthreads();
    ps[t] += v;
    __syncthreads();
  }
  int run = ps[t] - s;
  #pragma unroll
  for (int i = 0; i < 7; i++) {
    const int cid = t * 7 + i;
    if (cid < NCELL) { cellstart[b * 1729 + cid] = run; run += local[i]; }
  }
  if (t == 255) cellstart[b * 1729 + NCELL] = ps[255];
}

// ---------------------------------------------------------------------------
// K0c: counting-sort scatter -> qorder + sorted xyz float4
// ---------------------------------------------------------------------------
__global__ __launch_bounds__(256) void k0c_scatter(
    const float* __restrict__ xyz, const int* __restrict__ cellstart,
    int* __restrict__ cellfill, int* __restrict__ qorder,
    float4* __restrict__ xyzs)
{
  const int pt = blockIdx.x * 256 + threadIdx.x;
  const float x = xyz[pt * 3], y = xyz[pt * 3 + 1], z = xyz[pt * 3 + 2];
  const int b = pt >> 12;
  const int cid = cell_of(x, y, z);
  const int slot = atomicAdd(&cellfill[b * NCELL + cid], 1);
  const int pos = b * NPTS + cellstart[b * 1729 + cid] + slot;
  qorder[pos] = pt;
  xyzs[pos] = make_float4(x, y, z, 0.f);
}

// ---------------------------------------------------------------------------
// K2: dense-window KPConv.  2048 blocks x 256 thr (4 waves), 16 sorted
// queries/block, ~68 KB LDS -> 2 blocks/CU.
//  prologue: cell bbox of the 16 queries (+1) -> x-row ranges -> cpos[]
//  per 32-candidate chunk:
//    A) stage F^T[c][n] bf16 (coalesced feats reads via qorder) and
//       eval S[q*16+k][n] = bf16 influence (0 outside radius / tail / k=15)
//    B) MFMA 16x16x32: wave w owns c-tile w; 16 M-tiles accumulate in regs
//  writeback: D -> wf[q][c*16+k] bf16
//  p3: out[16][128] = wf[16][1024] @ Wt^T via MFMA (K=1024, 32 iters)
//  epilogue: BN partial atomics + scatter store via qm[]
// ---------------------------------------------------------------------------
__global__ __launch_bounds__(256, 2) void k2_conv(
    const float4* __restrict__ xyzs, const float* __restrict__ feats,
    const float* __restrict__ kpts, const int* __restrict__ cellstart,
    const int* __restrict__ qorder, const unsigned short* __restrict__ Wt,
    float* __restrict__ out, float* __restrict__ psum,
    float* __restrict__ psumsq)
{
  __shared__ short          wf[16][WFPAD];     // 33024 B
  __shared__ short          S[256][SPAD];      // 20480 B
  __shared__ short          FT[64][FTPAD];     //  4608 B
  __shared__ unsigned short cpos[4096];        //  8192 B
  __shared__ float4         qd[16];            //   256 B
  __shared__ int            qm[16];
  __shared__ float          kp[NKP][4];        //   240 B
  __shared__ int            rowrs[MAXROWS], rowlen[MAXROWS], pfx[MAXROWS + 1];
  __shared__ int            meta[6];           // ylo yspan zlo xlo xhi nrows

  const int tid = threadIdx.x;
  const int w   = tid >> 6;
  const int L   = tid & 63;
  const int m0  = blockIdx.x * 16;
  const int b   = m0 >> 12;

  if (tid < NKP * 3) {
    int k = tid / 3, c = tid - k * 3;
    kp[k][c] = kpts[tid];
  }
  if (tid < 16) {
    qd[tid] = xyzs[m0 + tid];
    qm[tid] = qorder[m0 + tid];
  }
  __syncthreads();

  if (tid == 0) {
    int x0 = 12, x1 = -1, y0 = 12, y1 = -1, z0 = 12, z1 = -1;
    for (int i = 0; i < 16; i++) {
      const float4 Q = qd[i];
      int cx = (int)(Q.x * 12.f); cx = cx > 11 ? 11 : cx;
      int cy = (int)(Q.y * 12.f); cy = cy > 11 ? 11 : cy;
      int cz = (int)(Q.z * 12.f); cz = cz > 11 ? 11 : cz;
      x0 = cx < x0 ? cx : x0; x1 = cx > x1 ? cx : x1;
      y0 = cy < y0 ? cy : y0; y1 = cy > y1 ? cy : y1;
      z0 = cz < z0 ? cz : z0; z1 = cz > z1 ? cz : z1;
    }
    x0 = x0 > 0 ? x0 - 1 : 0;  x1 = x1 < 11 ? x1 + 1 : 11;
    y0 = y0 > 0 ? y0 - 1 : 0;  y1 = y1 < 11 ? y1 + 1 : 11;
    z0 = z0 > 0 ? z0 - 1 : 0;  z1 = z1 < 11 ? z1 + 1 : 11;
    int nr = (y1 - y0 + 1) * (z1 - z0 + 1);
    meta[0] = y0; meta[1] = y1 - y0 + 1; meta[2] = z0;
    meta[3] = x0; meta[4] = x1;
    meta[5] = nr > MAXROWS ? MAXROWS : nr;
  }
  __syncthreads();

  const int nrows = meta[5], yspan = meta[1];
  if (tid < nrows) {
    const int z = meta[2] + tid / yspan, y = meta[0] + tid % yspan;
    const int base = b * 1729 + (z * 12 + y) * 12;
    const int rs = cellstart[base + meta[3]];
    rowrs[tid]  = rs;
    rowlen[tid] = cellstart[base + meta[4] + 1] - rs;
  }
  __syncthreads();
  if (tid == 0) {
    int run = 0;
    for (int r = 0; r < nrows; r++) { pfx[r] = run; run += rowlen[r]; }
    pfx[nrows] = run;
  }
  __syncthreads();
  if (tid < nrows) {
    const int rs = rowrs[tid], len = rowlen[tid], o = pfx[tid];
    for (int i = 0; i < len; i++) cpos[o + i] = (unsigned short)(rs + i);
  }
  __syncthreads();
  const int T = pfx[nrows];

  // per-wave stage-1 accumulators: 16 M-tiles (queries), this wave's c-tile
  f32x4_t acc[16];
  #pragma unroll
  for (int mt = 0; mt < 16; mt++) acc[mt] = (f32x4_t){0.f, 0.f, 0.f, 0.f};

  const int ln = L & 15;
  const int kh = L >> 4;

  for (int cb = 0; cb < T; cb += 32) {
    // ---- phase A: stage FT + eval S ----
    {
      // FT: c = tid&63, rows i = ii*4 + (tid>>6)
      const int c  = tid & 63;
      const int i0 = tid >> 6;
      int origs[8];
      #pragma unroll
      for (int ii = 0; ii < 8; ii++) {
        const int t = cb + ii * 4 + i0;
        origs[ii] = (t < T) ? qorder[b * NPTS + (int)cpos[t]] : -1;
      }
      #pragma unroll
      for (int ii = 0; ii < 8; ii++) {
        const int i = ii * 4 + i0;
        FT[c][i] = (origs[ii] >= 0)
                       ? (short)f2bf(feats[(size_t)origs[ii] * CIN + c])
                       : (short)0;
      }
    }
    #pragma unroll
    for (int rep = 0; rep < 2; rep++) {
      const int p = rep * 256 + tid;       // 512 slots = 16q x 32n
      const int q = p >> 5;
      const int n = p & 31;
      const int t = cb + n;
      float4 P = make_float4(1e6f, 1e6f, 1e6f, 0.f);
      if (t < T) P = xyzs[b * NPTS + (int)cpos[t]];
      const float4 Q = qd[q];
      const float rx = P.x - Q.x, ry = P.y - Q.y, rz = P.z - Q.z;
      #pragma unroll
      for (int k = 0; k < NKP; k++) {
        const float dx = rx - kp[k][0];
        const float dy = ry - kp[k][1];
        const float dz = rz - kp[k][2];
        const float wv =
            fmaxf(1.f - sqrtf(dx * dx + dy * dy + dz * dz) * KP_INV, 0.f);
        S[q * 16 + k][n] = (short)f2bf(wv);
      }
      S[q * 16 + 15][n] = 0;
    }
    __syncthreads();

    // ---- phase B: MFMA, wave w = c-tile w ----
    union { short4_t h[2]; bf16x8_t v; } bu;
    bu.h[0] = *(const short4_t*)&FT[w * 16 + ln][kh * 8];
    bu.h[1] = *(const short4_t*)&FT[w * 16 + ln][kh * 8 + 4];
    #pragma unroll
    for (int mt = 0; mt < 16; mt++) {
      bf16x8_t aa = *(const bf16x8_t*)&S[mt * 16 + ln][kh * 8];
      acc[mt] = __builtin_amdgcn_mfma_f32_16x16x32_bf16(aa, bu.v, acc[mt],
                                                        0, 0, 0);
    }
    __syncthreads();
  }

  // ---- writeback: D[m=q*?][col] -> wf[q][c*16+k], c = w*16+ln, k = kh*4+j
  #pragma unroll
  for (int mt = 0; mt < 16; mt++) {
    #pragma unroll
    for (int j = 0; j < 4; j++) {
      wf[mt][(w * 16 + ln) * 16 + kh * 4 + j] = (short)f2bf(acc[mt][j]);
    }
  }
  __syncthreads();

  // ---- p3: MFMA GEMM out[16][128] = wf[16][1024] @ Wt^T ----
  const int colbase = w * 32;

  f32x4_t acc2[2];
  acc2[0] = (f32x4_t){0.f, 0.f, 0.f, 0.f};
  acc2[1] = (f32x4_t){0.f, 0.f, 0.f, 0.f};

  const unsigned short* Bp0 = &Wt[(size_t)(colbase + ln) * KCP + kh * 8];
  const unsigned short* Bp1 = Bp0 + 16 * KCP;
  const short* Ap = &wf[ln][kh * 8];

  #pragma unroll 4
  for (int kk = 0; kk < 32; kk++) {
    const int ko = kk * 32;
    bf16x8_t b0 = *(const bf16x8_t*)(Bp0 + ko);
    bf16x8_t b1 = *(const bf16x8_t*)(Bp1 + ko);
    bf16x8_t a0 = *(const bf16x8_t*)(Ap + ko);
    acc2[0] = __builtin_amdgcn_mfma_f32_16x16x32_bf16(a0, b0, acc2[0], 0, 0, 0);
    acc2[1] = __builtin_amdgcn_mfma_f32_16x16x32_bf16(a0, b1, acc2[1], 0, 0, 0);
  }

  // BN partials: reduce 16 rows across kh via shfl, atomic into psum[128]
  float s0 = 0.f, q0 = 0.f, s1 = 0.f, q1 = 0.f;
  #pragma unroll
  for (int j = 0; j < 4; j++) {
    s0 += acc2[0][j]; q0 += acc2[0][j] * acc2[0][j];
    s1 += acc2[1][j]; q1 += acc2[1][j] * acc2[1][j];
  }
  s0 += __shfl_xor(s0, 16); s0 += __shfl_xor(s0, 32);
  q0 += __shfl_xor(q0, 16); q0 += __shfl_xor(q0, 32);
  s1 += __shfl_xor(s1, 16); s1 += __shfl_xor(s1, 32);
  q1 += __shfl_xor(q1, 16); q1 += __shfl_xor(q1, 32);
  if (kh == 0) {
    atomicAdd(&psum[colbase + ln], s0);
    atomicAdd(&psumsq[colbase + ln], q0);
    atomicAdd(&psum[colbase + 16 + ln], s1);
    atomicAdd(&psumsq[colbase + 16 + ln], q1);
  }

  // C/D layout: col = lane&15, row = (lane>>4)*4 + reg; scatter via qm[]
  #pragma unroll
  for (int c = 0; c < 2; c++) {
    #pragma unroll
    for (int j = 0; j < 4; j++) {
      const int row = kh * 4 + j;
      out[(size_t)qm[row] * COUT + colbase + c * 16 + ln] = acc2[c][j];
    }
  }
}

// ---------------------------------------------------------------------------
// K4: BN finalize (per-block, from psum) + normalize + LeakyReLU
// ---------------------------------------------------------------------------
__global__ __launch_bounds__(256) void k4_norm(
    float* __restrict__ out, const float* __restrict__ psum,
    const float* __restrict__ psumsq, const float* __restrict__ gamma,
    const float* __restrict__ beta)
{
  __shared__ float a_s[128], b_s[128];
  if (threadIdx.x < 128) {
    const int d = threadIdx.x;
    double mu  = (double)psum[d] / (double)M_TOT;
    double var = (double)psumsq[d] / (double)M_TOT - mu * mu;  // biased
    float rstd = (float)(1.0 / sqrt(var + 1e-5));
    float a = rstd * gamma[d];
    a_s[d] = a;
    b_s[d] = beta[d] - (float)mu * a;
  }
  __syncthreads();
  const int idx = blockIdx.x * 256 + threadIdx.x;   // float4 index
  float4 v = ((const float4*)out)[idx];
  const int d0 = (idx * 4) & 127;
  float y0 = v.x * a_s[d0 + 0] + b_s[d0 + 0];
  float y1 = v.y * a_s[d0 + 1] + b_s[d0 + 1];
  float y2 = v.z * a_s[d0 + 2] + b_s[d0 + 2];
  float y3 = v.w * a_s[d0 + 3] + b_s[d0 + 3];
  v.x = y0 >= 0.f ? y0 : NEG_SLOPE * y0;
  v.y = y1 >= 0.f ? y1 : NEG_SLOPE * y1;
  v.z = y2 >= 0.f ? y2 : NEG_SLOPE * y2;
  v.w = y3 >= 0.f ? y3 : NEG_SLOPE * y3;
  ((float4*)out)[idx] = v;
}

// ---------------------------------------------------------------------------
extern "C" void kernel_launch(void* const* d_in, const int* in_sizes, int n_in,
                              void* d_out, int out_size, void* d_ws,
                              size_t ws_size, hipStream_t stream)
{
  const float* xyz   = (const float*)d_in[0];
  const float* feats = (const float*)d_in[1];
  const float* kpts  = (const float*)d_in[2];
  const float* W     = (const float*)d_in[3];
  const float* gamma = (const float*)d_in[4];
  const float* beta  = (const float*)d_in[5];
  float* out = (float*)d_out;

  char* ws = (char*)d_ws;
  int*            cellcnt   = (int*)(ws + 0);           //  55296 B ─┐
  int*            cellfill  = (int*)(ws + 55296);       //  55296 B  │ zeroed
  float*          psum      = (float*)(ws + 110592);    //    512 B  │
  float*          psumsq    = (float*)(ws + 111104);    //    512 B ─┘
  int*            cellstart = (int*)(ws + 111616);      //  55424 B
  int*            qorder    = (int*)(ws + 167040);      // 131072 B
  float4*         xyzs      = (float4*)(ws + 298112);   // 524288 B
  unsigned short* Wt        = (unsigned short*)(ws + 822400);  // 262144 B

  hipMemsetAsync(ws, 0, 111616, stream);

  k0a_hist   <<< 128, 256, 0, stream>>>(xyz, cellcnt);
  k0b_scan_kW<<<  40, 256, 0, stream>>>(cellcnt, cellstart, W, Wt);
  k0c_scatter<<< 128, 256, 0, stream>>>(xyz, cellstart, cellfill, qorder,
                                        xyzs);
  k2_conv    <<<2048, 256, 0, stream>>>(xyzs, feats, kpts, cellstart, qorder,
                                        Wt, out, psum, psumsq);
  k4_norm    <<<(out_size / 4) / 256, 256, 0, stream>>>(out, psum, psumsq,
                                                        gamma, beta);
}

// Round 10
// 202.837 us; speedup vs baseline: 2.5356x; 2.5356x over previous
//
#include <hip/hip_runtime.h>

// KPConv simple block: grid ball query + sparse-MFMA KPConv + BN + LeakyReLU
// B=8, N=4096 -> M=32768; C_IN=64, C_OUT=128, K=15 kernel pts.
//
// Exact simplification: influence w = max(1 - d/0.04, 0) with ||kp||<=0.042
// => neighbors with ||rel|| >= 0.082 contribute 0; unordered within-0.082
// set == reference top-k result.  Neighbor cap 32 (P(any query >32) ~2e-4,
// Poisson(9.46); R9 showed densifying over the ~300-candidate window is a
// 10x VALU regression -- sparsity is the asset).
//
// R10: stage-1 as per-query MFMA GEMM over the capped list:
//   wf[k][c] = sum_nn wA[k][nn] * F[nn][c],  M=16(k) N=64(c) K=32(nn)
// = 4 MFMA/query.  Replaces R3-R8's LDS broadcast (~144 ds_read_b128 per
// query-wave -> ~17 LDS ops).  FT is wave-private (no barrier).  Stage-2
// uses kc' = c*16+k ordering (K=1024) so stage-1 D packs into b64 writes.

#define NB     8
#define NPTS   4096
#define M_TOT  32768
#define CIN    64
#define COUT   128
#define NKP    15
#define NN32   32              // neighbor cap (see header)
#define NCELL  1728            // 12^3
#define R2EFF  (0.082f * 0.082f)
#define KP_INV 25.0f           // 1 / KP_EXTENT(0.04)
#define NEG_SLOPE 0.2f
#define KCP    1024            // kc' = c*16+k (k=15 slots zero)
#define WFPAD  1032            // wf row stride (shorts), 16B-aligned
#define NP     40              // wA/FT col pad (80B rows: 2-way banks, free)

typedef float f32x4_t __attribute__((ext_vector_type(4)));
typedef short bf16x8_t __attribute__((ext_vector_type(8)));

__device__ __forceinline__ unsigned short f2bf(float f) {
  union { float f; unsigned u; } v; v.f = f;
  unsigned r = v.u + 0x7FFF + ((v.u >> 16) & 1);   // RNE
  return (unsigned short)(r >> 16);
}
__device__ __forceinline__ int cell_of(float x, float y, float z) {
  int cx = (int)(x * 12.f); cx = cx > 11 ? 11 : cx;
  int cy = (int)(y * 12.f); cy = cy > 11 ? 11 : cy;
  int cz = (int)(z * 12.f); cz = cz > 11 ? 11 : cz;
  return (cz * 12 + cy) * 12 + cx;
}

// ---------------------------------------------------------------------------
// K0a: per-cell histogram
// ---------------------------------------------------------------------------
__global__ __launch_bounds__(256) void k0a_hist(
    const float* __restrict__ xyz, int* __restrict__ cellcnt)
{
  const int pt = blockIdx.x * 256 + threadIdx.x;
  const float x = xyz[pt * 3], y = xyz[pt * 3 + 1], z = xyz[pt * 3 + 2];
  const int b = pt >> 12;
  atomicAdd(&cellcnt[b * NCELL + cell_of(x, y, z)], 1);
}

// ---------------------------------------------------------------------------
// K0b: blocks 0..7 = per-batch exclusive scan; blocks 8..39 = W -> Wt
// Wt[d][c*16+k] bf16, k=15 slot zero.
// ---------------------------------------------------------------------------
__global__ __launch_bounds__(256) void k0b_scan_kW(
    const int* __restrict__ cellcnt, int* __restrict__ cellstart,
    const float* __restrict__ W, unsigned short* __restrict__ Wt)
{
  if (blockIdx.x >= 8) {
    const int idx = (blockIdx.x - 8) * 256 + threadIdx.x;  // 8192
    const int d = idx & 127, c = idx >> 7;                 // c 0..63
    union { unsigned short s[16]; uint4 v[2]; } u;
    #pragma unroll
    for (int k = 0; k < NKP; k++)
      u.s[k] = f2bf(W[(size_t)k * (CIN * COUT) + c * COUT + d]);
    u.s[15] = 0;
    uint4* dst = (uint4*)&Wt[(size_t)d * KCP + c * 16];
    dst[0] = u.v[0]; dst[1] = u.v[1];
    return;
  }
  __shared__ int ps[256];
  const int b = blockIdx.x, t = threadIdx.x;
  int local[7], s = 0;
  #pragma unroll
  for (int i = 0; i < 7; i++) {
    const int cid = t * 7 + i;
    const int c = (cid < NCELL) ? cellcnt[b * NCELL + cid] : 0;
    local[i] = c; s += c;
  }
  ps[t] = s; __syncthreads();
  for (int off = 1; off < 256; off <<= 1) {
    int v = (t >= off) ? ps[t - off] : 0;
    __syncthreads();
    ps[t] += v;
    __syncthreads();
  }
  int run = ps[t] - s;
  #pragma unroll
  for (int i = 0; i < 7; i++) {
    const int cid = t * 7 + i;
    if (cid < NCELL) { cellstart[b * 1729 + cid] = run; run += local[i]; }
  }
  if (t == 255) cellstart[b * 1729 + NCELL] = ps[255];
}

// ---------------------------------------------------------------------------
// K0c: counting-sort scatter -> qorder + sorted xyz + sorted bf16 feats
// ---------------------------------------------------------------------------
__global__ __launch_bounds__(256) void k0c_scatter(
    const float* __restrict__ xyz, const float* __restrict__ feats,
    const int* __restrict__ cellstart, int* __restrict__ cellfill,
    int* __restrict__ qorder, float4* __restrict__ xyzs,
    unsigned short* __restrict__ fsorted)
{
  const int pt = blockIdx.x * 256 + threadIdx.x;
  const float x = xyz[pt * 3], y = xyz[pt * 3 + 1], z = xyz[pt * 3 + 2];
  const int b = pt >> 12;
  const int cid = cell_of(x, y, z);
  const int slot = atomicAdd(&cellfill[b * NCELL + cid], 1);
  const int pos = b * NPTS + cellstart[b * 1729 + cid] + slot;
  qorder[pos] = pt;
  xyzs[pos] = make_float4(x, y, z, 0.f);
  const float* src = &feats[(size_t)pt * CIN];
  uint4* dst = (uint4*)&fsorted[(size_t)pos * CIN];
  #pragma unroll
  for (int g = 0; g < 8; g++) {
    float4 a = *(const float4*)(src + g * 8);
    float4 c = *(const float4*)(src + g * 8 + 4);
    union { unsigned short s[8]; uint4 v; } u;
    u.s[0] = f2bf(a.x); u.s[1] = f2bf(a.y); u.s[2] = f2bf(a.z); u.s[3] = f2bf(a.w);
    u.s[4] = f2bf(c.x); u.s[5] = f2bf(c.y); u.s[6] = f2bf(c.z); u.s[7] = f2bf(c.w);
    dst[g] = u.v;
  }
}

// ---------------------------------------------------------------------------
// K1: grid ball query, one WAVE per query (ballot-compacted, no atomics).
// ---------------------------------------------------------------------------
__global__ __launch_bounds__(256) void k1_grid(
    const float4* __restrict__ xyzs, const int* __restrict__ cellstart,
    unsigned short* __restrict__ nlist, int* __restrict__ ncnt)
{
  const int m = blockIdx.x * 4 + (threadIdx.x >> 6);   // sorted query pos
  const int L = threadIdx.x & 63;
  const int b = m >> 12;
  const float4 Q = xyzs[m];
  int cx = (int)(Q.x * 12.f); cx = cx > 11 ? 11 : cx;
  int cy = (int)(Q.y * 12.f); cy = cy > 11 ? 11 : cy;
  int cz = (int)(Q.z * 12.f); cz = cz > 11 ? 11 : cz;

  int r0v = 0, lenv = 0;
  if (L < 9) {
    const int ny = cy + (L % 3) - 1;
    const int nz = cz + (L / 3) - 1;
    if (ny >= 0 && ny < 12 && nz >= 0 && nz < 12) {
      const int xlo = cx > 0 ? cx - 1 : 0;
      const int xhi = cx < 11 ? cx + 1 : 11;
      const int base = b * 1729 + (nz * 12 + ny) * 12;
      r0v  = cellstart[base + xlo];
      lenv = cellstart[base + xhi + 1] - r0v;
    }
  }
  int r0a[9], pfxa[10];
  pfxa[0] = 0;
  #pragma unroll
  for (int i = 0; i < 9; i++) {
    r0a[i] = __shfl(r0v, i);
    pfxa[i + 1] = pfxa[i] + __shfl(lenv, i);
  }
  const int T = pfxa[9];

  int cnt = 0;
  for (int tb = 0; tb < T; tb += 64) {
    const int t = tb + L;
    bool hit = false; int pos = 0;
    if (t < T) {
      int r = 0;
      #pragma unroll
      for (int i = 1; i < 9; i++) r += (t >= pfxa[i]);
      pos = r0a[r] + t - pfxa[r];
      const float4 P = xyzs[b * NPTS + pos];
      const float dx = P.x - Q.x, dy = P.y - Q.y, dz = P.z - Q.z;
      hit = (dx * dx + dy * dy + dz * dz) <= R2EFF;
    }
    const unsigned long long mask = __ballot(hit);
    if (hit) {
      const int slot = cnt + __popcll(mask & ((1ull << L) - 1ull));
      if (slot < NN32)
        nlist[(size_t)m * NN32 + slot] = (unsigned short)(b * NPTS + pos);
    }
    cnt += __popcll(mask);
  }
  if (L == 0) ncnt[m] = cnt > NN32 ? NN32 : cnt;
}

// ---------------------------------------------------------------------------
// K2: sparse-MFMA KPConv.  2048 blocks x 256 thr (4 waves), 16 sorted
// queries/block, ~75 KB LDS -> 2 blocks/CU.
//  p1) dense over 16q x 32nn slots: gidx + wA[q][k][nn] bf16 (zeros on pad)
//  p2) per wave, per query: 8 coalesced bf16 gather-rows -> FT (wave-private,
//      b64 packs, no barrier); 1 MFMA per c-tile (4) -> wf[q][c*16+k] b64
//  p3) MFMA GEMM out[16][128] = wf[16][1024] @ Wt^T (32 iters)
//  epilogue: BN partial atomics + scatter store via qm[]
// ---------------------------------------------------------------------------
__global__ __launch_bounds__(256, 2) void k2_conv(
    const float4* __restrict__ xyzs, const unsigned short* __restrict__ fsorted,
    const float* __restrict__ kpts, const unsigned short* __restrict__ nlist,
    const int* __restrict__ ncnt, const int* __restrict__ qorder,
    const unsigned short* __restrict__ Wt, float* __restrict__ out,
    float* __restrict__ psum, float* __restrict__ psumsq)
{
  __shared__ short  wf[16][WFPAD];       // 33024 B
  __shared__ short  wA[16][16][NP];      // 20480 B  weights bf16, A layout
  __shared__ short  FT[4][64][NP];       // 20480 B  per-wave features (B)
  __shared__ int    gidx[16][NN32];      //  2048 B
  __shared__ float4 qd[16];              //   256 B
  __shared__ int    qm[16];
  __shared__ int    cnts[16];
  __shared__ float  kp[NKP][4];          //   240 B

  const int tid = threadIdx.x;
  const int w   = tid >> 6;
  const int L   = tid & 63;
  const int m0  = blockIdx.x * 16;

  if (tid < NKP * 3) {
    int k = tid / 3, c = tid - k * 3;
    kp[k][c] = kpts[tid];
  }
  if (tid < 16) {
    qd[tid] = xyzs[m0 + tid];
    qm[tid] = qorder[m0 + tid];
    cnts[tid] = ncnt[m0 + tid];
  }
  __syncthreads();

  // ---- p1: 512 slots = 16q x 32nn -> gidx + wA ----
  #pragma unroll
  for (int rep = 0; rep < 2; rep++) {
    const int p = rep * 256 + tid;
    const int q  = p >> 5;
    const int nn = p & 31;
    if (nn < cnts[q]) {
      const int g = (int)nlist[(size_t)(m0 + q) * NN32 + nn];
      gidx[q][nn] = g;
      const float4 P = xyzs[g];
      const float4 Qx = qd[q];
      const float rx = P.x - Qx.x, ry = P.y - Qx.y, rz = P.z - Qx.z;
      #pragma unroll
      for (int k = 0; k < NKP; k++) {
        const float dx = rx - kp[k][0];
        const float dy = ry - kp[k][1];
        const float dz = rz - kp[k][2];
        const float wv =
            fmaxf(1.f - sqrtf(dx * dx + dy * dy + dz * dz) * KP_INV, 0.f);
        wA[q][k][nn] = (short)f2bf(wv);
      }
      wA[q][15][nn] = 0;
    } else {
      gidx[q][nn] = m0 + q;               // self: valid row, zero weights
      #pragma unroll
      for (int k = 0; k < 16; k++) wA[q][k][nn] = 0;
    }
  }
  __syncthreads();

  // ---- p2: per-query MFMA  wf[k][c] = wA[k][nn] x F[nn][c] ----
  const int ln = L & 15;
  const int kh = L >> 4;

  for (int qi = 0; qi < 4; qi++) {
    const int q = w * 4 + qi;
    // gather 32 neighbor rows, lane = channel; pack 4 nn per b64 write
    #pragma unroll
    for (int i = 0; i < 8; i++) {
      const int4 gg = *(const int4*)&gidx[q][i * 4];
      const unsigned short f0 = fsorted[(size_t)gg.x * CIN + L];
      const unsigned short f1 = fsorted[(size_t)gg.y * CIN + L];
      const unsigned short f2 = fsorted[(size_t)gg.z * CIN + L];
      const unsigned short f3 = fsorted[(size_t)gg.w * CIN + L];
      union { unsigned short s[4]; unsigned long long d; } u;
      u.s[0] = f0; u.s[1] = f1; u.s[2] = f2; u.s[3] = f3;
      *(unsigned long long*)&FT[w][L][i * 4] = u.d;
    }
    // wave-private FT: in-order DS pipe => no barrier needed
    bf16x8_t a = *(const bf16x8_t*)&wA[q][ln][kh * 8];
    f32x4_t aq[4];
    #pragma unroll
    for (int t = 0; t < 4; t++) aq[t] = (f32x4_t){0.f, 0.f, 0.f, 0.f};
    #pragma unroll
    for (int t = 0; t < 4; t++) {
      bf16x8_t bb = *(const bf16x8_t*)&FT[w][t * 16 + ln][kh * 8];
      aq[t] = __builtin_amdgcn_mfma_f32_16x16x32_bf16(a, bb, aq[t], 0, 0, 0);
    }
    // D[m=k][n=c] -> wf[q][c*16+k]; c = t*16+ln, k = kh*4+j (b64 pack over j)
    #pragma unroll
    for (int t = 0; t < 4; t++) {
      union { unsigned short s[4]; unsigned long long d; } u;
      #pragma unroll
      for (int j = 0; j < 4; j++) u.s[j] = f2bf(aq[t][j]);
      *(unsigned long long*)&wf[q][(t * 16 + ln) * 16 + kh * 4] = u.d;
    }
  }
  __syncthreads();

  // ---- p3: MFMA GEMM out[16][128] = wf[16][1024] @ Wt^T ----
  const int colbase = w * 32;

  f32x4_t acc2[2];
  acc2[0] = (f32x4_t){0.f, 0.f, 0.f, 0.f};
  acc2[1] = (f32x4_t){0.f, 0.f, 0.f, 0.f};

  const unsigned short* Bp0 = &Wt[(size_t)(colbase + ln) * KCP + kh * 8];
  const unsigned short* Bp1 = Bp0 + 16 * KCP;
  const short* Ap = &wf[ln][kh * 8];

  #pragma unroll 4
  for (int kk = 0; kk < 32; kk++) {
    const int ko = kk * 32;
    bf16x8_t b0 = *(const bf16x8_t*)(Bp0 + ko);
    bf16x8_t b1 = *(const bf16x8_t*)(Bp1 + ko);
    bf16x8_t a0 = *(const bf16x8_t*)(Ap + ko);
    acc2[0] = __builtin_amdgcn_mfma_f32_16x16x32_bf16(a0, b0, acc2[0], 0, 0, 0);
    acc2[1] = __builtin_amdgcn_mfma_f32_16x16x32_bf16(a0, b1, acc2[1], 0, 0, 0);
  }

  // BN partials: reduce 16 rows across kh via shfl, atomic into psum[128]
  float s0 = 0.f, q0 = 0.f, s1 = 0.f, q1 = 0.f;
  #pragma unroll
  for (int j = 0; j < 4; j++) {
    s0 += acc2[0][j]; q0 += acc2[0][j] * acc2[0][j];
    s1 += acc2[1][j]; q1 += acc2[1][j] * acc2[1][j];
  }
  s0 += __shfl_xor(s0, 16); s0 += __shfl_xor(s0, 32);
  q0 += __shfl_xor(q0, 16); q0 += __shfl_xor(q0, 32);
  s1 += __shfl_xor(s1, 16); s1 += __shfl_xor(s1, 32);
  q1 += __shfl_xor(q1, 16); q1 += __shfl_xor(q1, 32);
  if (kh == 0) {
    atomicAdd(&psum[colbase + ln], s0);
    atomicAdd(&psumsq[colbase + ln], q0);
    atomicAdd(&psum[colbase + 16 + ln], s1);
    atomicAdd(&psumsq[colbase + 16 + ln], q1);
  }

  // C/D layout: col = lane&15, row = (lane>>4)*4 + reg; scatter via qm[]
  #pragma unroll
  for (int c = 0; c < 2; c++) {
    #pragma unroll
    for (int j = 0; j < 4; j++) {
      const int row = kh * 4 + j;
      out[(size_t)qm[row] * COUT + colbase + c * 16 + ln] = acc2[c][j];
    }
  }
}

// ---------------------------------------------------------------------------
// K4: BN finalize (per-block, from psum) + normalize + LeakyReLU
// ---------------------------------------------------------------------------
__global__ __launch_bounds__(256) void k4_norm(
    float* __restrict__ out, const float* __restrict__ psum,
    const float* __restrict__ psumsq, const float* __restrict__ gamma,
    const float* __restrict__ beta)
{
  __shared__ float a_s[128], b_s[128];
  if (threadIdx.x < 128) {
    const int d = threadIdx.x;
    double mu  = (double)psum[d] / (double)M_TOT;
    double var = (double)psumsq[d] / (double)M_TOT - mu * mu;  // biased
    float rstd = (float)(1.0 / sqrt(var + 1e-5));
    float a = rstd * gamma[d];
    a_s[d] = a;
    b_s[d] = beta[d] - (float)mu * a;
  }
  __syncthreads();
  const int idx = blockIdx.x * 256 + threadIdx.x;   // float4 index
  float4 v = ((const float4*)out)[idx];
  const int d0 = (idx * 4) & 127;
  float y0 = v.x * a_s[d0 + 0] + b_s[d0 + 0];
  float y1 = v.y * a_s[d0 + 1] + b_s[d0 + 1];
  float y2 = v.z * a_s[d0 + 2] + b_s[d0 + 2];
  float y3 = v.w * a_s[d0 + 3] + b_s[d0 + 3];
  v.x = y0 >= 0.f ? y0 : NEG_SLOPE * y0;
  v.y = y1 >= 0.f ? y1 : NEG_SLOPE * y1;
  v.z = y2 >= 0.f ? y2 : NEG_SLOPE * y2;
  v.w = y3 >= 0.f ? y3 : NEG_SLOPE * y3;
  ((float4*)out)[idx] = v;
}

// ---------------------------------------------------------------------------
extern "C" void kernel_launch(void* const* d_in, const int* in_sizes, int n_in,
                              void* d_out, int out_size, void* d_ws,
                              size_t ws_size, hipStream_t stream)
{
  const float* xyz   = (const float*)d_in[0];
  const float* feats = (const float*)d_in[1];
  const float* kpts  = (const float*)d_in[2];
  const float* W     = (const float*)d_in[3];
  const float* gamma = (const float*)d_in[4];
  const float* beta  = (const float*)d_in[5];
  float* out = (float*)d_out;

  char* ws = (char*)d_ws;
  int*            cellcnt   = (int*)(ws + 0);           //  55296 B ─┐
  int*            cellfill  = (int*)(ws + 55296);       //  55296 B  │ zeroed
  float*          psum      = (float*)(ws + 110592);    //    512 B  │
  float*          psumsq    = (float*)(ws + 111104);    //    512 B ─┘
  int*            cellstart = (int*)(ws + 111616);      //  55424 B
  int*            qorder    = (int*)(ws + 167040);      // 131072 B
  float4*         xyzs      = (float4*)(ws + 298112);   // 524288 B
  unsigned short* fsorted   = (unsigned short*)(ws + 822400);   // 4194304 B
  unsigned short* Wt        = (unsigned short*)(ws + 5016704);  // 262144 B
  unsigned short* nlist     = (unsigned short*)(ws + 5278848);  // 2097152 B
  int*            ncnt      = (int*)(ws + 7376000);     // 131072 B

  hipMemsetAsync(ws, 0, 111616, stream);

  k0a_hist   <<< 128, 256, 0, stream>>>(xyz, cellcnt);
  k0b_scan_kW<<<  40, 256, 0, stream>>>(cellcnt, cellstart, W, Wt);
  k0c_scatter<<< 128, 256, 0, stream>>>(xyz, feats, cellstart, cellfill,
                                        qorder, xyzs, fsorted);
  k1_grid    <<<8192, 256, 0, stream>>>(xyzs, cellstart, nlist, ncnt);
  k2_conv    <<<2048, 256, 0, stream>>>(xyzs, fsorted, kpts, nlist, ncnt,
                                        qorder, Wt, out, psum, psumsq);
  k4_norm    <<<(out_size / 4) / 256, 256, 0, stream>>>(out, psum, psumsq,
                                                        gamma, beta);
}

// Round 11
// 202.719 us; speedup vs baseline: 2.5371x; 1.0006x over previous
//
#include <hip/hip_runtime.h>

// KPConv simple block: grid + block-union MFMA KPConv + BN + LeakyReLU
// B=8, N=4096 -> M=32768; C_IN=64, C_OUT=128, K=15 kernel pts.
//
// Exact simplification: influence w = max(1 - d/0.04, 0) with ||kp||<=0.042
// => candidates with ||rel|| >= 0.082 contribute 0 to every kernel point;
// the within-0.082 set == reference top-k result.
//
// R11: per block (16 sorted queries), compute the EXACT UNION of neighbor
// sets (branch-free min-d2-over-16 test on the cell-bbox window, ballot-free
// LDS-atomic compaction; U ~ 50-90).  Stage-1 = R9's verified chunked MFMA
// (S[16q*16k][32u] x FT[32u][64c]) but over the union (2-3 chunks), not the
// window (9-12) -- kills R10's 512 redundant per-query gather-rows AND the
// whole k1/nlist/fsorted pipeline.  LDS phase-aliased (~35 KB -> 3-4
// blocks/CU).  Stage-2 (kc'=c*16+k, K=1024) + epilogue unchanged from R10.

#define NB     8
#define NPTS   4096
#define M_TOT  32768
#define CIN    64
#define COUT   128
#define NKP    15
#define NCELL  1728            // 12^3
#define MAXROWS 64
#define UCAP   512             // union cap (mean ~70, Poisson tail ~0)
#define R2EFF  (0.082f * 0.082f)
#define KP_INV 25.0f           // 1 / KP_EXTENT(0.04)
#define NEG_SLOPE 0.2f
#define KCP    1024            // kc' = c*16+k (k=15 slots zero)
#define WFPAD  1032            // wf row stride (shorts), 16B-aligned
#define SP     40              // S/FT row stride (shorts), 80B

typedef float f32x4_t __attribute__((ext_vector_type(4)));
typedef short bf16x8_t __attribute__((ext_vector_type(8)));

__device__ __forceinline__ unsigned short f2bf(float f) {
  union { float f; unsigned u; } v; v.f = f;
  unsigned r = v.u + 0x7FFF + ((v.u >> 16) & 1);   // RNE
  return (unsigned short)(r >> 16);
}
__device__ __forceinline__ int cell_of(float x, float y, float z) {
  int cx = (int)(x * 12.f); cx = cx > 11 ? 11 : cx;
  int cy = (int)(y * 12.f); cy = cy > 11 ? 11 : cy;
  int cz = (int)(z * 12.f); cz = cz > 11 ? 11 : cz;
  return (cz * 12 + cy) * 12 + cx;
}

// ---------------------------------------------------------------------------
// K0a: per-cell histogram
// ---------------------------------------------------------------------------
__global__ __launch_bounds__(256) void k0a_hist(
    const float* __restrict__ xyz, int* __restrict__ cellcnt)
{
  const int pt = blockIdx.x * 256 + threadIdx.x;
  const float x = xyz[pt * 3], y = xyz[pt * 3 + 1], z = xyz[pt * 3 + 2];
  const int b = pt >> 12;
  atomicAdd(&cellcnt[b * NCELL + cell_of(x, y, z)], 1);
}

// ---------------------------------------------------------------------------
// K0b: blocks 0..7 = per-batch exclusive scan; blocks 8..39 = W -> Wt
// Wt[d][c*16+k] bf16, k=15 slot zero.
// ---------------------------------------------------------------------------
__global__ __launch_bounds__(256) void k0b_scan_kW(
    const int* __restrict__ cellcnt, int* __restrict__ cellstart,
    const float* __restrict__ W, unsigned short* __restrict__ Wt)
{
  if (blockIdx.x >= 8) {
    const int idx = (blockIdx.x - 8) * 256 + threadIdx.x;  // 8192
    const int d = idx & 127, c = idx >> 7;                 // c 0..63
    union { unsigned short s[16]; uint4 v[2]; } u;
    #pragma unroll
    for (int k = 0; k < NKP; k++)
      u.s[k] = f2bf(W[(size_t)k * (CIN * COUT) + c * COUT + d]);
    u.s[15] = 0;
    uint4* dst = (uint4*)&Wt[(size_t)d * KCP + c * 16];
    dst[0] = u.v[0]; dst[1] = u.v[1];
    return;
  }
  __shared__ int ps[256];
  const int b = blockIdx.x, t = threadIdx.x;
  int local[7], s = 0;
  #pragma unroll
  for (int i = 0; i < 7; i++) {
    const int cid = t * 7 + i;
    const int c = (cid < NCELL) ? cellcnt[b * NCELL + cid] : 0;
    local[i] = c; s += c;
  }
  ps[t] = s; __syncthreads();
  for (int off = 1; off < 256; off <<= 1) {
    int v = (t >= off) ? ps[t - off] : 0;
    __syncthreads();
    ps[t] += v;
    __syncthreads();
  }
  int run = ps[t] - s;
  #pragma unroll
  for (int i = 0; i < 7; i++) {
    const int cid = t * 7 + i;
    if (cid < NCELL) { cellstart[b * 1729 + cid] = run; run += local[i]; }
  }
  if (t == 255) cellstart[b * 1729 + NCELL] = ps[255];
}

// ---------------------------------------------------------------------------
// K0c: counting-sort scatter -> qorder + sorted xyz float4 (no feats pass)
// ---------------------------------------------------------------------------
__global__ __launch_bounds__(256) void k0c_scatter(
    const float* __restrict__ xyz, const int* __restrict__ cellstart,
    int* __restrict__ cellfill, int* __restrict__ qorder,
    float4* __restrict__ xyzs)
{
  const int pt = blockIdx.x * 256 + threadIdx.x;
  const float x = xyz[pt * 3], y = xyz[pt * 3 + 1], z = xyz[pt * 3 + 2];
  const int b = pt >> 12;
  const int cid = cell_of(x, y, z);
  const int slot = atomicAdd(&cellfill[b * NCELL + cid], 1);
  const int pos = b * NPTS + cellstart[b * 1729 + cid] + slot;
  qorder[pos] = pt;
  xyzs[pos] = make_float4(x, y, z, 0.f);
}

// ---------------------------------------------------------------------------
// K2: block-union MFMA KPConv.  2048 blocks x 256 thr (4 waves), 16 sorted
// queries/block, ~35 KB LDS (phase-aliased) -> 3-4 blocks/CU.
//   prologue: cell bbox (+1) -> x-row ranges -> cpos[] (R9-verified)
//   search:   any-hit (min d2 over 16 queries) per candidate -> Pu[] union
//   stage-1:  per 32-u chunk: FT[c][u] bf16 (coalesced feats) + S[q*16+k][u]
//             (sparse eval, zeros pad) -> 16 MFMA/wave, acc in regs
//   stage-2:  wf[q][c*16+k] (aliased LDS) @ Wt^T (K=1024) -> out + BN atomics
// ---------------------------------------------------------------------------
__global__ __launch_bounds__(256, 3) void k2_conv(
    const float4* __restrict__ xyzs, const float* __restrict__ feats,
    const float* __restrict__ kpts, const int* __restrict__ cellstart,
    const int* __restrict__ qorder, const unsigned short* __restrict__ Wt,
    float* __restrict__ out, float* __restrict__ psum,
    float* __restrict__ psumsq)
{
  // phase-aliased LDS:
  //   [0..8192)        Pu[512] float4      (search+stage-1)   | wf
  //   [8192..16384)    cpos[4096] ushort   (prologue+search)  | S (chunks)
  //   [8192..28672)    S[256][40] short    (chunks)           |
  //   [28672..33792)   FT[64][40] short    (chunks)           | (wf=33024)
  __shared__ char smraw[33792] __attribute__((aligned(16)));
  float4*         Pu   = (float4*)smraw;
  unsigned short* cpos = (unsigned short*)(smraw + 8192);
  short (*S)[SP]       = (short(*)[SP])(smraw + 8192);
  short (*FT)[SP]      = (short(*)[SP])(smraw + 28672);
  short (*wf)[WFPAD]   = (short(*)[WFPAD])smraw;

  __shared__ float4 qd[16];
  __shared__ int    qm[16];
  __shared__ float  kp[NKP][4];
  __shared__ int    rowrs[MAXROWS], rowlen[MAXROWS], pfx[MAXROWS + 1];
  __shared__ int    meta[6];
  __shared__ int    ucnt;

  const int tid = threadIdx.x;
  const int w   = tid >> 6;
  const int L   = tid & 63;
  const int m0  = blockIdx.x * 16;
  const int b   = m0 >> 12;

  if (tid < NKP * 3) {
    int k = tid / 3, c = tid - k * 3;
    kp[k][c] = kpts[tid];
  }
  if (tid < 16) {
    qd[tid] = xyzs[m0 + tid];
    qm[tid] = qorder[m0 + tid];
  }
  if (tid == 32) ucnt = 0;
  __syncthreads();

  if (tid == 0) {
    int x0 = 12, x1 = -1, y0 = 12, y1 = -1, z0 = 12, z1 = -1;
    for (int i = 0; i < 16; i++) {
      const float4 Q = qd[i];
      int cx = (int)(Q.x * 12.f); cx = cx > 11 ? 11 : cx;
      int cy = (int)(Q.y * 12.f); cy = cy > 11 ? 11 : cy;
      int cz = (int)(Q.z * 12.f); cz = cz > 11 ? 11 : cz;
      x0 = cx < x0 ? cx : x0; x1 = cx > x1 ? cx : x1;
      y0 = cy < y0 ? cy : y0; y1 = cy > y1 ? cy : y1;
      z0 = cz < z0 ? cz : z0; z1 = cz > z1 ? cz : z1;
    }
    x0 = x0 > 0 ? x0 - 1 : 0;  x1 = x1 < 11 ? x1 + 1 : 11;
    y0 = y0 > 0 ? y0 - 1 : 0;  y1 = y1 < 11 ? y1 + 1 : 11;
    z0 = z0 > 0 ? z0 - 1 : 0;  z1 = z1 < 11 ? z1 + 1 : 11;
    int nr = (y1 - y0 + 1) * (z1 - z0 + 1);
    meta[0] = y0; meta[1] = y1 - y0 + 1; meta[2] = z0;
    meta[3] = x0; meta[4] = x1;
    meta[5] = nr > MAXROWS ? MAXROWS : nr;
  }
  __syncthreads();

  const int nrows = meta[5], yspan = meta[1];
  if (tid < nrows) {
    const int z = meta[2] + tid / yspan, y = meta[0] + tid % yspan;
    const int base = b * 1729 + (z * 12 + y) * 12;
    const int rs = cellstart[base + meta[3]];
    rowrs[tid]  = rs;
    rowlen[tid] = cellstart[base + meta[4] + 1] - rs;
  }
  __syncthreads();
  if (tid == 0) {
    int run = 0;
    for (int r = 0; r < nrows; r++) { pfx[r] = run; run += rowlen[r]; }
    pfx[nrows] = run;
  }
  __syncthreads();
  if (tid < nrows) {
    const int rs = rowrs[tid], len = rowlen[tid], o = pfx[tid];
    for (int i = 0; i < len; i++) cpos[o + i] = (unsigned short)(rs + i);
  }
  __syncthreads();
  const int T = pfx[nrows];

  // ---- union search: any-hit over 16 queries, branch-free test ----
  for (int tb = 0; tb < T; tb += 256) {
    const int t = tb + tid;
    if (t < T) {
      const int pos = (int)cpos[t];
      const float4 P = xyzs[b * NPTS + pos];
      float best = 1e9f;
      #pragma unroll
      for (int i = 0; i < 16; i++) {
        const float4 Q = qd[i];
        const float dx = P.x - Q.x, dy = P.y - Q.y, dz = P.z - Q.z;
        best = fminf(best, dx * dx + dy * dy + dz * dz);
      }
      if (best <= R2EFF) {
        const int slot = atomicAdd(&ucnt, 1);
        if (slot < UCAP)
          Pu[slot] = make_float4(P.x, P.y, P.z, __int_as_float(pos));
      }
    }
  }
  __syncthreads();
  int U = ucnt; U = U > UCAP ? UCAP : U;

  // ---- stage-1: chunked MFMA over the union ----
  const int ln = L & 15;
  const int kh = L >> 4;

  f32x4_t acc[16];
  #pragma unroll
  for (int mt = 0; mt < 16; mt++) acc[mt] = (f32x4_t){0.f, 0.f, 0.f, 0.f};

  for (int ub = 0; ub < U; ub += 32) {
    // FT[c][i]: coalesced feats rows via qorder (row-uniform loads)
    {
      const int c  = tid & 63;
      const int i0 = tid >> 6;
      #pragma unroll
      for (int ii = 0; ii < 8; ii++) {
        const int i = ii * 4 + i0;
        const int u = ub + i;
        short v = 0;
        if (u < U) {
          const int pos  = __float_as_int(Pu[u].w);
          const int orig = qorder[b * NPTS + pos];
          v = (short)f2bf(feats[(size_t)orig * CIN + c]);
        }
        FT[c][i] = v;
      }
    }
    // S[q*16+k][n]: sparse influence eval (zeros outside radius / pad)
    #pragma unroll
    for (int rep = 0; rep < 2; rep++) {
      const int p = rep * 256 + tid;     // 512 = 16q x 32n
      const int q = p >> 5;
      const int n = p & 31;
      const int u = ub + n;
      if (u < U) {
        const float4 P = Pu[u];
        const float4 Q = qd[q];
        const float rx = P.x - Q.x, ry = P.y - Q.y, rz = P.z - Q.z;
        #pragma unroll
        for (int k = 0; k < NKP; k++) {
          const float dx = rx - kp[k][0];
          const float dy = ry - kp[k][1];
          const float dz = rz - kp[k][2];
          const float wv =
              fmaxf(1.f - sqrtf(dx * dx + dy * dy + dz * dz) * KP_INV, 0.f);
          S[q * 16 + k][n] = (short)f2bf(wv);
        }
        S[q * 16 + 15][n] = 0;
      } else {
        #pragma unroll
        for (int k = 0; k < 16; k++) S[q * 16 + k][n] = 0;
      }
    }
    __syncthreads();

    // MFMA: wave w = c-tile w; 16 query m-tiles
    bf16x8_t bb = *(const bf16x8_t*)&FT[w * 16 + ln][kh * 8];
    #pragma unroll
    for (int mt = 0; mt < 16; mt++) {
      bf16x8_t aa = *(const bf16x8_t*)&S[mt * 16 + ln][kh * 8];
      acc[mt] = __builtin_amdgcn_mfma_f32_16x16x32_bf16(aa, bb, acc[mt],
                                                        0, 0, 0);
    }
    __syncthreads();
  }

  // ---- writeback: D -> wf[q][c*16+k] (aliased region; S/FT/Pu dead) ----
  #pragma unroll
  for (int mt = 0; mt < 16; mt++) {
    union { unsigned short s[4]; unsigned long long d; } u;
    #pragma unroll
    for (int j = 0; j < 4; j++) u.s[j] = f2bf(acc[mt][j]);
    *(unsigned long long*)&wf[mt][(w * 16 + ln) * 16 + kh * 4] = u.d;
  }
  __syncthreads();

  // ---- stage-2: out[16][128] = wf[16][1024] @ Wt^T ----
  const int colbase = w * 32;

  f32x4_t acc2[2];
  acc2[0] = (f32x4_t){0.f, 0.f, 0.f, 0.f};
  acc2[1] = (f32x4_t){0.f, 0.f, 0.f, 0.f};

  const unsigned short* Bp0 = &Wt[(size_t)(colbase + ln) * KCP + kh * 8];
  const unsigned short* Bp1 = Bp0 + 16 * KCP;
  const short* Ap = &wf[ln][kh * 8];

  #pragma unroll 4
  for (int kk = 0; kk < 32; kk++) {
    const int ko = kk * 32;
    bf16x8_t b0 = *(const bf16x8_t*)(Bp0 + ko);
    bf16x8_t b1 = *(const bf16x8_t*)(Bp1 + ko);
    bf16x8_t a0 = *(const bf16x8_t*)(Ap + ko);
    acc2[0] = __builtin_amdgcn_mfma_f32_16x16x32_bf16(a0, b0, acc2[0], 0, 0, 0);
    acc2[1] = __builtin_amdgcn_mfma_f32_16x16x32_bf16(a0, b1, acc2[1], 0, 0, 0);
  }

  // BN partials: reduce 16 rows across kh via shfl, atomic into psum[128]
  float s0 = 0.f, q0 = 0.f, s1 = 0.f, q1 = 0.f;
  #pragma unroll
  for (int j = 0; j < 4; j++) {
    s0 += acc2[0][j]; q0 += acc2[0][j] * acc2[0][j];
    s1 += acc2[1][j]; q1 += acc2[1][j] * acc2[1][j];
  }
  s0 += __shfl_xor(s0, 16); s0 += __shfl_xor(s0, 32);
  q0 += __shfl_xor(q0, 16); q0 += __shfl_xor(q0, 32);
  s1 += __shfl_xor(s1, 16); s1 += __shfl_xor(s1, 32);
  q1 += __shfl_xor(q1, 16); q1 += __shfl_xor(q1, 32);
  if (kh == 0) {
    atomicAdd(&psum[colbase + ln], s0);
    atomicAdd(&psumsq[colbase + ln], q0);
    atomicAdd(&psum[colbase + 16 + ln], s1);
    atomicAdd(&psumsq[colbase + 16 + ln], q1);
  }

  // C/D layout: col = lane&15, row = (lane>>4)*4 + reg; scatter via qm[]
  #pragma unroll
  for (int c = 0; c < 2; c++) {
    #pragma unroll
    for (int j = 0; j < 4; j++) {
      const int row = kh * 4 + j;
      out[(size_t)qm[row] * COUT + colbase + c * 16 + ln] = acc2[c][j];
    }
  }
}

// ---------------------------------------------------------------------------
// K4: BN finalize (per-block, from psum) + normalize + LeakyReLU
// ---------------------------------------------------------------------------
__global__ __launch_bounds__(256) void k4_norm(
    float* __restrict__ out, const float* __restrict__ psum,
    const float* __restrict__ psumsq, const float* __restrict__ gamma,
    const float* __restrict__ beta)
{
  __shared__ float a_s[128], b_s[128];
  if (threadIdx.x < 128) {
    const int d = threadIdx.x;
    double mu  = (double)psum[d] / (double)M_TOT;
    double var = (double)psumsq[d] / (double)M_TOT - mu * mu;  // biased
    float rstd = (float)(1.0 / sqrt(var + 1e-5));
    float a = rstd * gamma[d];
    a_s[d] = a;
    b_s[d] = beta[d] - (float)mu * a;
  }
  __syncthreads();
  const int idx = blockIdx.x * 256 + threadIdx.x;   // float4 index
  float4 v = ((const float4*)out)[idx];
  const int d0 = (idx * 4) & 127;
  float y0 = v.x * a_s[d0 + 0] + b_s[d0 + 0];
  float y1 = v.y * a_s[d0 + 1] + b_s[d0 + 1];
  float y2 = v.z * a_s[d0 + 2] + b_s[d0 + 2];
  float y3 = v.w * a_s[d0 + 3] + b_s[d0 + 3];
  v.x = y0 >= 0.f ? y0 : NEG_SLOPE * y0;
  v.y = y1 >= 0.f ? y1 : NEG_SLOPE * y1;
  v.z = y2 >= 0.f ? y2 : NEG_SLOPE * y2;
  v.w = y3 >= 0.f ? y3 : NEG_SLOPE * y3;
  ((float4*)out)[idx] = v;
}

// ---------------------------------------------------------------------------
extern "C" void kernel_launch(void* const* d_in, const int* in_sizes, int n_in,
                              void* d_out, int out_size, void* d_ws,
                              size_t ws_size, hipStream_t stream)
{
  const float* xyz   = (const float*)d_in[0];
  const float* feats = (const float*)d_in[1];
  const float* kpts  = (const float*)d_in[2];
  const float* W     = (const float*)d_in[3];
  const float* gamma = (const float*)d_in[4];
  const float* beta  = (const float*)d_in[5];
  float* out = (float*)d_out;

  char* ws = (char*)d_ws;
  int*            cellcnt   = (int*)(ws + 0);           //  55296 B ─┐
  int*            cellfill  = (int*)(ws + 55296);       //  55296 B  │ zeroed
  float*          psum      = (float*)(ws + 110592);    //    512 B  │
  float*          psumsq    = (float*)(ws + 111104);    //    512 B ─┘
  int*            cellstart = (int*)(ws + 111616);      //  55424 B
  int*            qorder    = (int*)(ws + 167040);      // 131072 B
  float4*         xyzs      = (float4*)(ws + 298112);   // 524288 B
  unsigned short* Wt        = (unsigned short*)(ws + 822400);  // 262144 B

  hipMemsetAsync(ws, 0, 111616, stream);

  k0a_hist   <<< 128, 256, 0, stream>>>(xyz, cellcnt);
  k0b_scan_kW<<<  40, 256, 0, stream>>>(cellcnt, cellstart, W, Wt);
  k0c_scatter<<< 128, 256, 0, stream>>>(xyz, cellstart, cellfill, qorder,
                                        xyzs);
  k2_conv    <<<2048, 256, 0, stream>>>(xyzs, feats, kpts, cellstart, qorder,
                                        Wt, out, psum, psumsq);
  k4_norm    <<<(out_size / 4) / 256, 256, 0, stream>>>(out, psum, psumsq,
                                                        gamma, beta);
}

// Round 12
// 196.537 us; speedup vs baseline: 2.6169x; 1.0315x over previous
//
#include <hip/hip_runtime.h>

// KPConv simple block: grid + block-union MFMA KPConv + BN + LeakyReLU
// B=8, N=4096 -> M=32768; C_IN=64, C_OUT=128, K=15 kernel pts.
//
// Exact simplification: influence w = max(1 - d/0.04, 0) with ||kp||<=0.042
// => candidates with ||rel|| >= 0.082 contribute 0 to every kernel point;
// the within-0.082 set == reference top-k result.
//
// R12 = R11 core (block-union + chunked MFMA stage-1, kc' stage-2) with:
//  (1) __launch_bounds__(256,4): LDS 35 KB fits 4 blocks/CU (R11 declared 3)
//  (2) sorted bf16 feats restored (kf fused in k0c): FT staging reads are
//      spatially-local L2-hot bf16 (R11 gathered random fp32 rows from HBM
//      inside each chunk's barrier -> FETCH 19 MB, exposed ~900cyc)
//  (3) prologue rewritten wave-0-only: bbox shfl-xor reduce, per-lane row
//      ranges, 6-step shfl prefix scan, cpos by wave 0 -> 1 barrier (was 5,
//      incl. a tid0-serial pfx loop)

#define NB     8
#define NPTS   4096
#define M_TOT  32768
#define CIN    64
#define COUT   128
#define NKP    15
#define NCELL  1728            // 12^3
#define UCAP   512             // union cap (mean ~70)
#define R2EFF  (0.082f * 0.082f)
#define KP_INV 25.0f           // 1 / KP_EXTENT(0.04)
#define NEG_SLOPE 0.2f
#define KCP    1024            // kc' = c*16+k (k=15 slots zero)
#define WFPAD  1032            // wf row stride (shorts), 16B-aligned
#define SP     40              // S/FT row stride (shorts), 80B

typedef float f32x4_t __attribute__((ext_vector_type(4)));
typedef short bf16x8_t __attribute__((ext_vector_type(8)));

__device__ __forceinline__ unsigned short f2bf(float f) {
  union { float f; unsigned u; } v; v.f = f;
  unsigned r = v.u + 0x7FFF + ((v.u >> 16) & 1);   // RNE
  return (unsigned short)(r >> 16);
}
__device__ __forceinline__ int cell_of(float x, float y, float z) {
  int cx = (int)(x * 12.f); cx = cx > 11 ? 11 : cx;
  int cy = (int)(y * 12.f); cy = cy > 11 ? 11 : cy;
  int cz = (int)(z * 12.f); cz = cz > 11 ? 11 : cz;
  return (cz * 12 + cy) * 12 + cx;
}

// ---------------------------------------------------------------------------
// K0a: per-cell histogram
// ---------------------------------------------------------------------------
__global__ __launch_bounds__(256) void k0a_hist(
    const float* __restrict__ xyz, int* __restrict__ cellcnt)
{
  const int pt = blockIdx.x * 256 + threadIdx.x;
  const float x = xyz[pt * 3], y = xyz[pt * 3 + 1], z = xyz[pt * 3 + 2];
  const int b = pt >> 12;
  atomicAdd(&cellcnt[b * NCELL + cell_of(x, y, z)], 1);
}

// ---------------------------------------------------------------------------
// K0b: blocks 0..7 = per-batch exclusive scan; blocks 8..39 = W -> Wt
// Wt[d][c*16+k] bf16, k=15 slot zero.
// ---------------------------------------------------------------------------
__global__ __launch_bounds__(256) void k0b_scan_kW(
    const int* __restrict__ cellcnt, int* __restrict__ cellstart,
    const float* __restrict__ W, unsigned short* __restrict__ Wt)
{
  if (blockIdx.x >= 8) {
    const int idx = (blockIdx.x - 8) * 256 + threadIdx.x;  // 8192
    const int d = idx & 127, c = idx >> 7;                 // c 0..63
    union { unsigned short s[16]; uint4 v[2]; } u;
    #pragma unroll
    for (int k = 0; k < NKP; k++)
      u.s[k] = f2bf(W[(size_t)k * (CIN * COUT) + c * COUT + d]);
    u.s[15] = 0;
    uint4* dst = (uint4*)&Wt[(size_t)d * KCP + c * 16];
    dst[0] = u.v[0]; dst[1] = u.v[1];
    return;
  }
  __shared__ int ps[256];
  const int b = blockIdx.x, t = threadIdx.x;
  int local[7], s = 0;
  #pragma unroll
  for (int i = 0; i < 7; i++) {
    const int cid = t * 7 + i;
    const int c = (cid < NCELL) ? cellcnt[b * NCELL + cid] : 0;
    local[i] = c; s += c;
  }
  ps[t] = s; __syncthreads();
  for (int off = 1; off < 256; off <<= 1) {
    int v = (t >= off) ? ps[t - off] : 0;
    __syncthreads();
    ps[t] += v;
    __syncthreads();
  }
  int run = ps[t] - s;
  #pragma unroll
  for (int i = 0; i < 7; i++) {
    const int cid = t * 7 + i;
    if (cid < NCELL) { cellstart[b * 1729 + cid] = run; run += local[i]; }
  }
  if (t == 255) cellstart[b * 1729 + NCELL] = ps[255];
}

// ---------------------------------------------------------------------------
// K0c: counting-sort scatter -> qorder + sorted xyz + sorted bf16 feats
// ---------------------------------------------------------------------------
__global__ __launch_bounds__(256) void k0c_scatter(
    const float* __restrict__ xyz, const float* __restrict__ feats,
    const int* __restrict__ cellstart, int* __restrict__ cellfill,
    int* __restrict__ qorder, float4* __restrict__ xyzs,
    unsigned short* __restrict__ fsorted)
{
  const int pt = blockIdx.x * 256 + threadIdx.x;
  const float x = xyz[pt * 3], y = xyz[pt * 3 + 1], z = xyz[pt * 3 + 2];
  const int b = pt >> 12;
  const int cid = cell_of(x, y, z);
  const int slot = atomicAdd(&cellfill[b * NCELL + cid], 1);
  const int pos = b * NPTS + cellstart[b * 1729 + cid] + slot;
  qorder[pos] = pt;
  xyzs[pos] = make_float4(x, y, z, 0.f);
  const float* src = &feats[(size_t)pt * CIN];
  uint4* dst = (uint4*)&fsorted[(size_t)pos * CIN];
  #pragma unroll
  for (int g = 0; g < 8; g++) {
    float4 a = *(const float4*)(src + g * 8);
    float4 c = *(const float4*)(src + g * 8 + 4);
    union { unsigned short s[8]; uint4 v; } u;
    u.s[0] = f2bf(a.x); u.s[1] = f2bf(a.y); u.s[2] = f2bf(a.z); u.s[3] = f2bf(a.w);
    u.s[4] = f2bf(c.x); u.s[5] = f2bf(c.y); u.s[6] = f2bf(c.z); u.s[7] = f2bf(c.w);
    dst[g] = u.v;
  }
}

// ---------------------------------------------------------------------------
// K2: block-union MFMA KPConv.  2048 blocks x 256 thr (4 waves), 16 sorted
// queries/block, ~34 KB LDS (phase-aliased) -> 4 blocks/CU.
// ---------------------------------------------------------------------------
__global__ __launch_bounds__(256, 4) void k2_conv(
    const float4* __restrict__ xyzs, const unsigned short* __restrict__ fsorted,
    const float* __restrict__ kpts, const int* __restrict__ cellstart,
    const int* __restrict__ qorder, const unsigned short* __restrict__ Wt,
    float* __restrict__ out, float* __restrict__ psum,
    float* __restrict__ psumsq)
{
  // phase-aliased LDS:
  //   [0..8192)       Pu[512] float4    (search+stage-1)  | wf[16][1032]
  //   [8192..16384)   cpos[4096] ushort (prologue+search) | S[256][40]
  //   [28672..33792)  FT[64][40] short  (chunks)
  __shared__ char smraw[33792] __attribute__((aligned(16)));
  float4*         Pu   = (float4*)smraw;
  unsigned short* cpos = (unsigned short*)(smraw + 8192);
  short (*S)[SP]       = (short(*)[SP])(smraw + 8192);
  short (*FT)[SP]      = (short(*)[SP])(smraw + 28672);
  short (*wf)[WFPAD]   = (short(*)[WFPAD])smraw;

  __shared__ float4 qd[16];
  __shared__ int    qm[16];
  __shared__ float  kp[NKP][4];
  __shared__ int    Tsh;
  __shared__ int    ucnt;

  const int tid = threadIdx.x;
  const int w   = tid >> 6;
  const int L   = tid & 63;
  const int m0  = blockIdx.x * 16;
  const int b   = m0 >> 12;

  if (tid >= 64 && tid < 64 + NKP * 3) {
    const int t2 = tid - 64;
    kp[t2 / 3][t2 - (t2 / 3) * 3] = kpts[t2];
  }

  // ---- wave-0 prologue: bbox -> row ranges -> pfx (shfl scan) -> cpos ----
  if (tid < 64) {
    int cxm = 12, cym = 12, czm = 12, cxM = -1, cyM = -1, czM = -1;
    if (tid < 16) {
      const float4 Q = xyzs[m0 + tid];
      qd[tid] = Q;
      qm[tid] = qorder[m0 + tid];
      int a = (int)(Q.x * 12.f); a = a > 11 ? 11 : a;
      int c = (int)(Q.y * 12.f); c = c > 11 ? 11 : c;
      int d = (int)(Q.z * 12.f); d = d > 11 ? 11 : d;
      cxm = cxM = a; cym = cyM = c; czm = czM = d;
    }
    #pragma unroll
    for (int off = 8; off >= 1; off >>= 1) {
      int v;
      v = __shfl_xor(cxm, off); cxm = v < cxm ? v : cxm;
      v = __shfl_xor(cxM, off); cxM = v > cxM ? v : cxM;
      v = __shfl_xor(cym, off); cym = v < cym ? v : cym;
      v = __shfl_xor(cyM, off); cyM = v > cyM ? v : cyM;
      v = __shfl_xor(czm, off); czm = v < czm ? v : czm;
      v = __shfl_xor(czM, off); czM = v > czM ? v : czM;
    }
    cxm = __shfl(cxm, 0); cxM = __shfl(cxM, 0);
    cym = __shfl(cym, 0); cyM = __shfl(cyM, 0);
    czm = __shfl(czm, 0); czM = __shfl(czM, 0);

    const int x0 = cxm > 0 ? cxm - 1 : 0, x1 = cxM < 11 ? cxM + 1 : 11;
    const int y0 = cym > 0 ? cym - 1 : 0, y1 = cyM < 11 ? cyM + 1 : 11;
    const int z0 = czm > 0 ? czm - 1 : 0, z1 = czM < 11 ? czM + 1 : 11;
    const int yspan = y1 - y0 + 1;
    int nr = yspan * (z1 - z0 + 1);
    nr = nr > 64 ? 64 : nr;

    int rs = 0, len = 0;
    if (tid < nr) {
      const int zz = z0 + tid / yspan, yy = y0 + tid % yspan;
      const int base = b * 1729 + (zz * 12 + yy) * 12;
      rs  = cellstart[base + x0];
      len = cellstart[base + x1 + 1] - rs;
    }
    int incl = len;
    #pragma unroll
    for (int off = 1; off < 64; off <<= 1) {
      const int v = __shfl_up(incl, off);
      if (tid >= off) incl += v;
    }
    const int excl = incl - len;
    for (int i = 0; i < len; i++) cpos[excl + i] = (unsigned short)(rs + i);
    if (tid == 63) Tsh = incl;
    if (tid == 62) ucnt = 0;
  }
  __syncthreads();
  const int T = Tsh;

  // ---- union search: any-hit over 16 queries, branch-free test ----
  for (int tb = 0; tb < T; tb += 256) {
    const int t = tb + tid;
    if (t < T) {
      const int pos = (int)cpos[t];
      const float4 P = xyzs[b * NPTS + pos];
      float best = 1e9f;
      #pragma unroll
      for (int i = 0; i < 16; i++) {
        const float4 Q = qd[i];
        const float dx = P.x - Q.x, dy = P.y - Q.y, dz = P.z - Q.z;
        const float d2 = dx * dx + dy * dy + dz * dz;
        best = d2 < best ? d2 : best;
      }
      if (best <= R2EFF) {
        const int slot = atomicAdd(&ucnt, 1);
        if (slot < UCAP)
          Pu[slot] = make_float4(P.x, P.y, P.z, __int_as_float(pos));
      }
    }
  }
  __syncthreads();
  int U = ucnt; U = U > UCAP ? UCAP : U;

  // ---- stage-1: chunked MFMA over the union ----
  const int ln = L & 15;
  const int kh = L >> 4;

  f32x4_t acc[16];
  #pragma unroll
  for (int mt = 0; mt < 16; mt++) acc[mt] = (f32x4_t){0.f, 0.f, 0.f, 0.f};

  for (int ub = 0; ub < U; ub += 32) {
    // FT[c][i]: sorted bf16 rows (L2-hot, spatially local)
    {
      const int c  = tid & 63;
      const int i0 = tid >> 6;
      #pragma unroll
      for (int ii = 0; ii < 8; ii++) {
        const int i = ii * 4 + i0;
        const int u = ub + i;
        short v = 0;
        if (u < U) {
          const int pos = __float_as_int(Pu[u].w);
          v = (short)fsorted[(size_t)(b * NPTS + pos) * CIN + c];
        }
        FT[c][i] = v;
      }
    }
    // S[q*16+k][n]: sparse influence eval (zeros outside radius / pad)
    #pragma unroll
    for (int rep = 0; rep < 2; rep++) {
      const int p = rep * 256 + tid;     // 512 = 16q x 32n
      const int q = p >> 5;
      const int n = p & 31;
      const int u = ub + n;
      if (u < U) {
        const float4 P = Pu[u];
        const float4 Q = qd[q];
        const float rx = P.x - Q.x, ry = P.y - Q.y, rz = P.z - Q.z;
        #pragma unroll
        for (int k = 0; k < NKP; k++) {
          const float dx = rx - kp[k][0];
          const float dy = ry - kp[k][1];
          const float dz = rz - kp[k][2];
          const float wv =
              fmaxf(1.f - sqrtf(dx * dx + dy * dy + dz * dz) * KP_INV, 0.f);
          S[q * 16 + k][n] = (short)f2bf(wv);
        }
        S[q * 16 + 15][n] = 0;
      } else {
        #pragma unroll
        for (int k = 0; k < 16; k++) S[q * 16 + k][n] = 0;
      }
    }
    __syncthreads();

    // MFMA: wave w = c-tile w; 16 query m-tiles
    bf16x8_t bb = *(const bf16x8_t*)&FT[w * 16 + ln][kh * 8];
    #pragma unroll
    for (int mt = 0; mt < 16; mt++) {
      bf16x8_t aa = *(const bf16x8_t*)&S[mt * 16 + ln][kh * 8];
      acc[mt] = __builtin_amdgcn_mfma_f32_16x16x32_bf16(aa, bb, acc[mt],
                                                        0, 0, 0);
    }
    __syncthreads();
  }

  // ---- writeback: D -> wf[q][c*16+k] (aliased region; S/FT/Pu dead) ----
  #pragma unroll
  for (int mt = 0; mt < 16; mt++) {
    union { unsigned short s[4]; unsigned long long d; } u;
    #pragma unroll
    for (int j = 0; j < 4; j++) u.s[j] = f2bf(acc[mt][j]);
    *(unsigned long long*)&wf[mt][(w * 16 + ln) * 16 + kh * 4] = u.d;
  }
  __syncthreads();

  // ---- stage-2: out[16][128] = wf[16][1024] @ Wt^T ----
  const int colbase = w * 32;

  f32x4_t acc2[2];
  acc2[0] = (f32x4_t){0.f, 0.f, 0.f, 0.f};
  acc2[1] = (f32x4_t){0.f, 0.f, 0.f, 0.f};

  const unsigned short* Bp0 = &Wt[(size_t)(colbase + ln) * KCP + kh * 8];
  const unsigned short* Bp1 = Bp0 + 16 * KCP;
  const short* Ap = &wf[ln][kh * 8];

  #pragma unroll 4
  for (int kk = 0; kk < 32; kk++) {
    const int ko = kk * 32;
    bf16x8_t b0 = *(const bf16x8_t*)(Bp0 + ko);
    bf16x8_t b1 = *(const bf16x8_t*)(Bp1 + ko);
    bf16x8_t a0 = *(const bf16x8_t*)(Ap + ko);
    acc2[0] = __builtin_amdgcn_mfma_f32_16x16x32_bf16(a0, b0, acc2[0], 0, 0, 0);
    acc2[1] = __builtin_amdgcn_mfma_f32_16x16x32_bf16(a0, b1, acc2[1], 0, 0, 0);
  }

  // BN partials: reduce 16 rows across kh via shfl, atomic into psum[128]
  float s0 = 0.f, q0 = 0.f, s1 = 0.f, q1 = 0.f;
  #pragma unroll
  for (int j = 0; j < 4; j++) {
    s0 += acc2[0][j]; q0 += acc2[0][j] * acc2[0][j];
    s1 += acc2[1][j]; q1 += acc2[1][j] * acc2[1][j];
  }
  s0 += __shfl_xor(s0, 16); s0 += __shfl_xor(s0, 32);
  q0 += __shfl_xor(q0, 16); q0 += __shfl_xor(q0, 32);
  s1 += __shfl_xor(s1, 16); s1 += __shfl_xor(s1, 32);
  q1 += __shfl_xor(q1, 16); q1 += __shfl_xor(q1, 32);
  if (kh == 0) {
    atomicAdd(&psum[colbase + ln], s0);
    atomicAdd(&psumsq[colbase + ln], q0);
    atomicAdd(&psum[colbase + 16 + ln], s1);
    atomicAdd(&psumsq[colbase + 16 + ln], q1);
  }

  // C/D layout: col = lane&15, row = (lane>>4)*4 + reg; scatter via qm[]
  #pragma unroll
  for (int c = 0; c < 2; c++) {
    #pragma unroll
    for (int j = 0; j < 4; j++) {
      const int row = kh * 4 + j;
      out[(size_t)qm[row] * COUT + colbase + c * 16 + ln] = acc2[c][j];
    }
  }
}

// ---------------------------------------------------------------------------
// K4: BN finalize (per-block, from psum) + normalize + LeakyReLU
// ---------------------------------------------------------------------------
__global__ __launch_bounds__(256) void k4_norm(
    float* __restrict__ out, const float* __restrict__ psum,
    const float* __restrict__ psumsq, const float* __restrict__ gamma,
    const float* __restrict__ beta)
{
  __shared__ float a_s[128], b_s[128];
  if (threadIdx.x < 128) {
    const int d = threadIdx.x;
    double mu  = (double)psum[d] / (double)M_TOT;
    double var = (double)psumsq[d] / (double)M_TOT - mu * mu;  // biased
    float rstd = (float)(1.0 / sqrt(var + 1e-5));
    float a = rstd * gamma[d];
    a_s[d] = a;
    b_s[d] = beta[d] - (float)mu * a;
  }
  __syncthreads();
  const int idx = blockIdx.x * 256 + threadIdx.x;   // float4 index
  float4 v = ((const float4*)out)[idx];
  const int d0 = (idx * 4) & 127;
  float y0 = v.x * a_s[d0 + 0] + b_s[d0 + 0];
  float y1 = v.y * a_s[d0 + 1] + b_s[d0 + 1];
  float y2 = v.z * a_s[d0 + 2] + b_s[d0 + 2];
  float y3 = v.w * a_s[d0 + 3] + b_s[d0 + 3];
  v.x = y0 >= 0.f ? y0 : NEG_SLOPE * y0;
  v.y = y1 >= 0.f ? y1 : NEG_SLOPE * y1;
  v.z = y2 >= 0.f ? y2 : NEG_SLOPE * y2;
  v.w = y3 >= 0.f ? y3 : NEG_SLOPE * y3;
  ((float4*)out)[idx] = v;
}

// ---------------------------------------------------------------------------
extern "C" void kernel_launch(void* const* d_in, const int* in_sizes, int n_in,
                              void* d_out, int out_size, void* d_ws,
                              size_t ws_size, hipStream_t stream)
{
  const float* xyz   = (const float*)d_in[0];
  const float* feats = (const float*)d_in[1];
  const float* kpts  = (const float*)d_in[2];
  const float* W     = (const float*)d_in[3];
  const float* gamma = (const float*)d_in[4];
  const float* beta  = (const float*)d_in[5];
  float* out = (float*)d_out;

  char* ws = (char*)d_ws;
  int*            cellcnt   = (int*)(ws + 0);           //  55296 B ─┐
  int*            cellfill  = (int*)(ws + 55296);       //  55296 B  │ zeroed
  float*          psum      = (float*)(ws + 110592);    //    512 B  │
  float*          psumsq    = (float*)(ws + 111104);    //    512 B ─┘
  int*            cellstart = (int*)(ws + 111616);      //  55424 B
  int*            qorder    = (int*)(ws + 167040);      // 131072 B
  float4*         xyzs      = (float4*)(ws + 298112);   // 524288 B
  unsigned short* fsorted   = (unsigned short*)(ws + 822400);   // 4194304 B
  unsigned short* Wt        = (unsigned short*)(ws + 5016704);  // 262144 B

  hipMemsetAsync(ws, 0, 111616, stream);

  k0a_hist   <<< 128, 256, 0, stream>>>(xyz, cellcnt);
  k0b_scan_kW<<<  40, 256, 0, stream>>>(cellcnt, cellstart, W, Wt);
  k0c_scatter<<< 128, 256, 0, stream>>>(xyz, feats, cellstart, cellfill,
                                        qorder, xyzs, fsorted);
  k2_conv    <<<2048, 256, 0, stream>>>(xyzs, fsorted, kpts, cellstart,
                                        qorder, Wt, out, psum, psumsq);
  k4_norm    <<<(out_size / 4) / 256, 256, 0, stream>>>(out, psum, psumsq,
                                                        gamma, beta);
}